// Round 3
// baseline (574.214 us; speedup 1.0000x reference)
//
#include <hip/hip_runtime.h>

// Causal depthwise FIR conv, 512 taps, fp32.
// out[b,t,d] = sum_k filt[k,d] * X(t-k), X(m)=x[b,m,d] (m>=0) else last[512+m,d]

constexpr int CLEN  = 512;
constexpr int SEQ   = 4096;
constexpr int DIM   = 1024;
constexpr int BATCH = 4;

constexpr int NT     = 32;            // output times per thread
constexpr int DCH    = 256;           // channels per block (= threads per block)
constexpr int NCHUNK = CLEN / NT;     // 16 K-chunks

__global__ __launch_bounds__(DCH) void cconv_fir(
    const float* __restrict__ x,      // [BATCH][SEQ][DIM]
    const float* __restrict__ last,   // [CLEN][DIM]
    const float* __restrict__ filt,   // [CLEN][DIM]
    float* __restrict__ out)          // [BATCH][SEQ][DIM]
{
    // Bijective XCD-chunk swizzle: 2048 blocks, 8 XCDs -> 256 contiguous ids each.
    int bid = blockIdx.x;
    int id  = (bid & 7) * (int)(gridDim.x >> 3) + (bid >> 3);

    int tt = id & (SEQ / NT - 1);       // t-tile 0..127
    int dg = (id >> 7) & (DIM / DCH - 1); // d-group 0..3
    int b  = id >> 9;                   // batch 0..3

    int d  = dg * DCH + threadIdx.x;
    int t0 = tt * NT;

    const float* xb    = x + ((size_t)b * SEQ) * DIM;
    const float* lasts = last + (size_t)CLEN * DIM;  // lasts[r*DIM+d] valid for r in [-512,-1]

    float acc[NT];
    float hi[NT], lo[NT];
#pragma unroll
    for (int i = 0; i < NT; ++i) acc[i] = 0.f;

    // hi[i] = X(t0 + i - c*NT) at c=0  (always in-range: t0+i >= 0)
#pragma unroll
    for (int i = 0; i < NT; ++i) hi[i] = xb[(size_t)(t0 + i) * DIM + d];

    for (int c = 0; c < NCHUNK; ++c) {
        const int kbase = c * NT;

        // lo[i] = X(t0 + i - (c+1)*NT); row may be negative -> history.
        // r is wave-uniform per i (t0, c block-uniform) -> scalar base select.
#pragma unroll
        for (int i = 0; i < NT; ++i) {
            int r = t0 + i - (c + 1) * NT;
            const float* base = (r >= 0) ? xb : lasts;
            lo[i] = base[(ptrdiff_t)r * DIM + d];
        }

        // FMA block: chunk covers taps k = kbase + j, j in [0,NT)
#pragma unroll
        for (int jo = 0; jo < NT; jo += 8) {
            float fr[8];
#pragma unroll
            for (int jj = 0; jj < 8; ++jj)
                fr[jj] = filt[(size_t)(kbase + jo + jj) * DIM + d];
#pragma unroll
            for (int jj = 0; jj < 8; ++jj) {
                const int j = jo + jj;
#pragma unroll
                for (int i = 0; i < NT; ++i) {
                    float w = (i >= j) ? hi[i - j] : lo[NT + i - j];
                    acc[i] = fmaf(fr[jj], w, acc[i]);
                }
            }
        }

#pragma unroll
        for (int i = 0; i < NT; ++i) hi[i] = lo[i];
    }

    float* ob = out + ((size_t)b * SEQ) * DIM;
#pragma unroll
    for (int i = 0; i < NT; ++i)
        ob[(size_t)(t0 + i) * DIM + d] = acc[i];
}

extern "C" void kernel_launch(void* const* d_in, const int* in_sizes, int n_in,
                              void* d_out, int out_size, void* d_ws, size_t ws_size,
                              hipStream_t stream) {
    const float* x    = (const float*)d_in[0];
    const float* last = (const float*)d_in[1];
    const float* filt = (const float*)d_in[2];
    float* out        = (float*)d_out;

    const int nblocks = BATCH * (DIM / DCH) * (SEQ / NT);  // 4*4*128 = 2048
    cconv_fir<<<dim3(nblocks), dim3(DCH), 0, stream>>>(x, last, filt, out);
}

// Round 4
// 543.669 us; speedup vs baseline: 1.0562x; 1.0562x over previous
//
#include <hip/hip_runtime.h>

// Causal depthwise FIR conv, 512 taps, fp32, software-pipelined.
// out[b,t,d] = sum_k filt[k,d] * X(t-k), X(m)=x[b,m,d] (m>=0) else last[512+m,d]

constexpr int CLEN  = 512;
constexpr int SEQ   = 4096;
constexpr int DIM   = 1024;
constexpr int BATCH = 4;

constexpr int NT   = 32;           // output times per thread
constexpr int DCH  = 256;          // channels per block (= threads)
constexpr int NBLK = CLEN / NT;    // 16 K-chunks

// dst[i] = X(t0 + i - wb*NT) for this thread's channel
#define LOAD_BLK(dst, wb)                                         \
  _Pragma("unroll")                                               \
  for (int i = 0; i < NT; ++i) {                                  \
    int r = t0 + i - (wb)*NT;                                     \
    const float* base = (r >= 0) ? xd : ld;                       \
    dst[i] = base[(ptrdiff_t)r * DIM];                            \
  }

#define LOAD_FR(dst, kb)                                          \
  _Pragma("unroll")                                               \
  for (int j = 0; j < NT; ++j)                                    \
    dst[j] = fd[(size_t)((kb) + j) * DIM];

// Upper triangle: taps j vs outputs i>=j, uses resident hi block only.
#define UFMA(fr, hi)                                              \
  _Pragma("unroll")                                               \
  for (int j = 0; j < NT; ++j)                                    \
    _Pragma("unroll")                                             \
    for (int i = j; i < NT; ++i)                                  \
      acc[i] = fmaf(fr[j], hi[i - j], acc[i]);

// Lower triangle: outputs i<j, uses the freshly loaded lo block.
#define LFMA(fr, lo)                                              \
  _Pragma("unroll")                                               \
  for (int j = 1; j < NT; ++j)                                    \
    _Pragma("unroll")                                             \
    for (int i = 0; i < j; ++i)                                   \
      acc[i] = fmaf(fr[j], lo[NT + i - j], acc[i]);

__global__ __launch_bounds__(DCH, 2) void cconv_fir(
    const float* __restrict__ x,      // [BATCH][SEQ][DIM]
    const float* __restrict__ last,   // [CLEN][DIM]
    const float* __restrict__ filt,   // [CLEN][DIM]
    float* __restrict__ out)          // [BATCH][SEQ][DIM]
{
    // Bijective XCD-chunk swizzle: 2048 blocks, 8 XCDs -> 256 contiguous ids each.
    int bid = blockIdx.x;
    int id  = (bid & 7) * (int)(gridDim.x >> 3) + (bid >> 3);

    int tt = id & (SEQ / NT - 1);          // t-tile 0..127
    int dg = (id >> 7) & (DIM / DCH - 1);  // d-group
    int b  = id >> 9;                      // batch

    int d  = dg * DCH + threadIdx.x;
    int t0 = tt * NT;

    const float* xd = x + ((size_t)b * SEQ) * DIM + d;
    const float* ld = last + (size_t)CLEN * DIM + d;  // ld[r*DIM] valid for r in [-512,-1]
    const float* fd = filt + d;

    float acc[NT];
#pragma unroll
    for (int i = 0; i < NT; ++i) acc[i] = 0.f;

    float wA[NT], wB[NT], fA[NT], fB[NT];

    // Prologue: block 0 (hi of chunk 0) and its taps.
    LOAD_BLK(wA, 0)
    LOAD_FR(fA, 0)

#pragma unroll 1
    for (int wp = 0; wp < NBLK; wp += 2) {
        // ---- chunk wp: hi=wA, lo=wB ----
        LOAD_BLK(wB, wp + 1)                 // wp+1 <= 15, filt rows in-bounds
        { int kb = (wp + 1) * NT; LOAD_FR(fB, kb) }
        UFMA(fA, wA)                         // ~1056 cyc hides wB/fB latency
        LFMA(fA, wB)
        // ---- chunk wp+1: hi=wB, lo=wA ----
        LOAD_BLK(wA, wp + 2)                 // block 16 read is legal (history/x range)
        { int kb = (wp + 2) * NT;
          if (kb > CLEN - NT) kb = CLEN - NT;  // clamp: row 16 would be OOB; values unused
          LOAD_FR(fA, kb) }
        UFMA(fB, wB)
        LFMA(fB, wA)
    }

    float* ob = out + ((size_t)b * SEQ) * DIM + d;
#pragma unroll
    for (int i = 0; i < NT; ++i)
        ob[(size_t)(t0 + i) * DIM] = acc[i];
}

extern "C" void kernel_launch(void* const* d_in, const int* in_sizes, int n_in,
                              void* d_out, int out_size, void* d_ws, size_t ws_size,
                              hipStream_t stream) {
    const float* x    = (const float*)d_in[0];
    const float* last = (const float*)d_in[1];
    const float* filt = (const float*)d_in[2];
    float* out        = (float*)d_out;

    const int nblocks = BATCH * (DIM / DCH) * (SEQ / NT);  // 2048
    cconv_fir<<<dim3(nblocks), dim3(DCH), 0, stream>>>(x, last, filt, out);
}